// Round 8
// baseline (121.140 us; speedup 1.0000x reference)
//
#include <hip/hip_runtime.h>
#include <hip/hip_bf16.h>

#define NB 8
#define BIN 512
#define BOUT 512
#define BATCH 8192
#define DIM 4096   // NB*BIN

typedef __attribute__((ext_vector_type(8))) short bf16x8;
typedef __attribute__((ext_vector_type(4))) float f32x4;

#define SWZ16(r) (((r) & 15) << 4)

__device__ __forceinline__ unsigned short f2bf(float f) {
    return __builtin_bit_cast(unsigned short, __float2bfloat16(f));
}

__device__ __forceinline__ unsigned long long pack4(f32x4 f) {
    return (unsigned long long)f2bf(f.x)
         | ((unsigned long long)f2bf(f.y) << 16)
         | ((unsigned long long)f2bf(f.z) << 32)
         | ((unsigned long long)f2bf(f.w) << 48);
}

__device__ __forceinline__ void gload16(const void* g, void* l) {
    __builtin_amdgcn_global_load_lds(
        (const __attribute__((address_space(1))) unsigned int*)g,
        (__attribute__((address_space(3))) unsigned int*)l, 16, 0, 0);
}

// ---------------- weight pack ----------------
// New layout: pk[nb][kidx 0..15][slot 0..31][lane 0..63][8 ushort]
// slot = wn*4 + nf  (wn = wave 0..7 owning 64 cols, nf = 16-col fragment 0..3)
// fragment content: lane -> row = wn*64 + nf*16 + (lane&15), col = kidx*32 + (lane>>4)*8
// One k-tile (kidx) = 32 KB, linear => direct global_load_lds staging.
__global__ void pack_w(const float* __restrict__ W, unsigned short* __restrict__ pk) {
    int gid = blockIdx.x * 256 + threadIdx.x;        // 262144 total
    int lane = gid & 63;
    int s5   = (gid >> 6) & 31;
    int kidx = (gid >> 11) & 15;
    int nb   = gid >> 15;
    int wn = s5 >> 2, nf = s5 & 3;
    int row = wn * 64 + nf * 16 + (lane & 15);
    int col = kidx * 32 + (lane >> 4) * 8;
    const float* s = W + ((size_t)nb * BOUT + row) * BIN + col;
    f32x4 a = *(const f32x4*)s;
    f32x4 b = *(const f32x4*)(s + 4);
    unsigned long long* d = (unsigned long long*)(pk + (size_t)gid * 8);
    d[0] = pack4(a);
    d[1] = pack4(b);
}

// ---------------- fused 2-layer block-diag MLP ----------------
// wg: 64 batch rows x one full diagonal block (512 cols). 512 threads = 8 waves,
// wave wid owns cols wid*64..+64 (N=64), all waves share all 64 rows (M=64).
// Per wave acc = 4x4 f32x4 (64 regs). A (x then h) lives in XH LDS (64 KB,
// SWZ16-swizzled, shared). W staged tile-by-tile (32 KB, k=32) via
// global_load_lds into a 3-slot ring: prefetch depth 2, counted vmcnt(4) per
// step (never 0 until the end) so W loads stay in flight across barriers.
__global__ __launch_bounds__(512, 2)
void fused_mlp(const float* __restrict__ X,
               const unsigned short* __restrict__ PK1,
               const float* __restrict__ B1,
               const unsigned short* __restrict__ PK2,
               const float* __restrict__ B2,
               float* __restrict__ Out)
{
    __shared__ __align__(16) unsigned char POOL[163840];  // 64 KB XH + 3x32 KB ring
    unsigned char* XH = POOL;
    unsigned char* RG = POOL + 65536;

    const int bid = blockIdx.x;
    const int nb = bid & 7;       // XCD pin: bid%8 round-robin -> W slice resident per-XCD
    const int mt = bid >> 3;      // 0..127

    const int t = threadIdx.x;
    const int lane = t & 63;
    const int wid = t >> 6;       // 0..7 -> col slice wid*64
    const int l15 = lane & 15;
    const int lhi = lane >> 4;

    const int row0 = mt * 64;
    const int wc0  = nb * 512;

    const unsigned short* pk1 = PK1 + (size_t)nb * 262144;   // 16 tiles x 16384 ush
    const unsigned short* pk2 = PK2 + (size_t)nb * 262144;

    // ---- bias preload FIRST (keeps vmcnt ledger clean in the main loop) ----
    float bv1[4], bv2[4];
    #pragma unroll
    for (int n = 0; n < 4; n++) {
        const int c = wc0 + wid * 64 + n * 16 + l15;
        bv1[n] = B1[c];
        bv2[n] = B2[c];
    }

    // A-read bases: r = m*16+l15; addr = ab[m][kk&3] + (kk>>2)*256
    int ab[4][4];
    #pragma unroll
    for (int m = 0; m < 4; m++) {
        const int r_ = m * 16 + l15;
        #pragma unroll
        for (int p = 0; p < 4; p++)
            ab[m][p] = r_ * 1024 + ((p * 64 + lhi * 16) ^ SWZ16(r_));
    }

    const int wg_g = wid * 2048 + lane * 8;   // ushort offset of this wave's stage region
    const int wl_l = wid * 4096;              // LDS byte offset (wave-uniform)
    const int bptr = wid * 4096 + lane * 16;  // B fragment read base within a tile

    f32x4 acc[4][4];
    #pragma unroll
    for (int m = 0; m < 4; m++)
        #pragma unroll
        for (int n = 0; n < 4; n++)
            acc[m][n] = (f32x4)(0.f);

#define ISSUE(G) { \
    const unsigned short* tb_ = ((G) < 16 ? pk1 : pk2) + ((G) & 15) * 16384 + wg_g; \
    unsigned char* lb_ = RG + ((G) % 3) * 32768 + wl_l; \
    _Pragma("unroll") for (int i_ = 0; i_ < 4; i_++) \
        gload16(tb_ + i_ * 512, lb_ + i_ * 1024); }

#define BAR() { \
    asm volatile("s_waitcnt lgkmcnt(0)" ::: "memory"); \
    __builtin_amdgcn_s_barrier(); \
    __builtin_amdgcn_sched_barrier(0); }

#define STEP(G) { \
    if ((G) == 31) { asm volatile("s_waitcnt vmcnt(0)" ::: "memory"); } \
    else           { asm volatile("s_waitcnt vmcnt(4)" ::: "memory"); } \
    __builtin_amdgcn_s_barrier(); \
    __builtin_amdgcn_sched_barrier(0); \
    if ((G) + 2 <= 31) ISSUE((G) + 2); \
    const unsigned char* wb_ = RG + ((G) % 3) * 32768; \
    bf16x8 bfr[4]; \
    _Pragma("unroll") for (int n_ = 0; n_ < 4; n_++) \
        bfr[n_] = *(const bf16x8*)(wb_ + bptr + n_ * 1024); \
    bf16x8 af[4]; \
    const int kk_ = (G) & 15; \
    _Pragma("unroll") for (int m_ = 0; m_ < 4; m_++) \
        af[m_] = *(const bf16x8*)(XH + ab[m_][kk_ & 3] + (kk_ >> 2) * 256); \
    __builtin_amdgcn_s_setprio(1); \
    _Pragma("unroll") for (int m_ = 0; m_ < 4; m_++) \
        _Pragma("unroll") for (int n_ = 0; n_ < 4; n_++) \
            acc[m_][n_] = __builtin_amdgcn_mfma_f32_16x16x32_bf16(af[m_], bfr[n_], acc[m_][n_], 0, 0, 0); \
    __builtin_amdgcn_s_setprio(0); }

    // ---- prologue: issue W1 tiles 0,1; stage x; barrier ----
    ISSUE(0);
    ISSUE(1);
    {
        // 512 threads stage [64 rows][512 f32] -> bf16 swizzled into XH
        const int sr = t >> 3;
        const int c0 = (t & 7) * 64;                 // f32 col base
        const float* xr = X + (size_t)(row0 + sr) * DIM + wc0 + c0;
        #pragma unroll
        for (int i = 0; i < 8; i++) {
            f32x4 a = *(const f32x4*)(xr + i * 8);
            f32x4 b = *(const f32x4*)(xr + i * 8 + 4);
            bf16x8 v;
            ((unsigned long long*)&v)[0] = pack4(a);
            ((unsigned long long*)&v)[1] = pack4(b);
            *(bf16x8*)(XH + sr * 1024 + ((((c0 + i * 8) * 2)) ^ SWZ16(sr))) = v;
        }
    }
    BAR();

    // ================= phase 1: acc = x @ W1^T =================
    #pragma unroll
    for (int g = 0; g < 16; g++) STEP(g);

    BAR();   // all waves done reading XH(x) -> safe to overwrite with h

    // ---- h = relu(acc + b1) -> XH (same swizzled layout) ----
    #pragma unroll
    for (int n = 0; n < 4; n++) {
        const int c = wid * 64 + n * 16 + l15;
        #pragma unroll
        for (int m = 0; m < 4; m++) {
            #pragma unroll
            for (int rr = 0; rr < 4; rr++) {
                float v = acc[m][n][rr] + bv1[n];
                v = v > 0.f ? v : 0.f;
                const int r = m * 16 + lhi * 4 + rr;
                *(unsigned short*)(XH + r * 1024 + ((c * 2) ^ SWZ16(r))) = f2bf(v);
            }
        }
    }
    BAR();   // h visible to all waves

    #pragma unroll
    for (int m = 0; m < 4; m++)
        #pragma unroll
        for (int n = 0; n < 4; n++)
            acc[m][n] = (f32x4)(0.f);

    // ================= phase 2: acc = h @ W2^T =================
    #pragma unroll
    for (int g = 16; g < 32; g++) STEP(g);

    // ---- epilogue: out = relu(acc + b2), f32 ----
    #pragma unroll
    for (int n = 0; n < 4; n++) {
        const int c = wc0 + wid * 64 + n * 16 + l15;
        #pragma unroll
        for (int m = 0; m < 4; m++) {
            const int rb = row0 + m * 16 + lhi * 4;
            #pragma unroll
            for (int rr = 0; rr < 4; rr++) {
                float v = acc[m][n][rr] + bv2[n];
                Out[(size_t)(rb + rr) * DIM + c] = v > 0.f ? v : 0.f;
            }
        }
    }

#undef ISSUE
#undef BAR
#undef STEP
}

extern "C" void kernel_launch(void* const* d_in, const int* in_sizes, int n_in,
                              void* d_out, int out_size, void* d_ws, size_t ws_size,
                              hipStream_t stream) {
    const float* x  = (const float*)d_in[0];
    const float* W1 = (const float*)d_in[1];
    const float* b1 = (const float*)d_in[2];
    const float* W2 = (const float*)d_in[3];
    const float* b2 = (const float*)d_in[4];
    float* out = (float*)d_out;

    char* ws = (char*)d_ws;
    unsigned short* PK1 = (unsigned short*)ws;                 // 4 MB
    unsigned short* PK2 = (unsigned short*)(ws + (4u << 20));  // 4 MB

    pack_w<<<1024, 256, 0, stream>>>(W1, PK1);
    pack_w<<<1024, 256, 0, stream>>>(W2, PK2);

    const int GRID = NB * (BATCH / 64);     // 1024
    fused_mlp<<<GRID, 512, 0, stream>>>(x, PK1, b1, PK2, b2, out);
}